// Round 5
// baseline (169.902 us; speedup 1.0000x reference)
//
#include <hip/hip_runtime.h>
#include <math.h>

#define NCAM 6
#define C_CH 64
#define HF   64
#define WF   176
#define GDIM 129
#define NY   4
#define NH   3
#define DD   128
#define WDIM 128
#define NP   (DD*WDIM)

#define ROWB (WF*C_CH*4)          // integral row stride, bytes
#define COLB (C_CH*4)             // integral col stride, bytes
#define IMGB ((size_t)HF*WF*C_CH*4)

// BoxP: 4 row + 4 col byte offsets into the channel-last integral image,
// 4 lerp weights, gated area. 64B; wave-uniform scalar-loaded.
struct alignas(16) BoxP {
    int   r0, r1, r2, r3;   // yT0,yT1,yB0,yB1 row byte offsets
    int   c0, c1, c2, c3;   // xL0,xL1,xR0,xR1 col byte offsets
    float wxL, wxR, wyT, wyB;
    float area;
    int   pad0, pad1, pad2;
};
static_assert(sizeof(BoxP) == 64, "BoxP size");

__device__ __forceinline__ int rfl_i(int x) {
    return __builtin_amdgcn_readfirstlane(x);
}
__device__ __forceinline__ float rfl_f(float x) {
    return __builtin_bit_cast(float, __builtin_amdgcn_readfirstlane(__builtin_bit_cast(int, x)));
}

// ---------------- Kernel 1: row cumsum (axis=-1) -> channel-last rowsum ----------------
__global__ __launch_bounds__(256) void k_rowcum(const float* __restrict__ feat,
                                                float* __restrict__ rowsum)
{
    __shared__ float T[WF * 65];
    __shared__ float S[4][C_CH];
    __shared__ float OFF[4][C_CH];
    const int h   = blockIdx.x;
    const int n   = blockIdx.y;
    const int tid = threadIdx.x;

    for (int idx = tid; idx < C_CH * WF; idx += 256) {
        const int cc = idx / WF;
        const int w  = idx % WF;
        T[w*65 + cc] = feat[((size_t)(n*C_CH + cc)*HF + h)*WF + w];
    }
    __syncthreads();
    {
        const int cc = tid & 63, seg = tid >> 6;
        const int w0 = seg * 44;
        float run = 0.0f;
        #pragma unroll
        for (int i = 0; i < 44; ++i) {
            run += T[(w0 + i)*65 + cc];
            T[(w0 + i)*65 + cc] = run;
        }
        S[seg][cc] = run;
    }
    __syncthreads();
    {
        const int cc = tid & 63, seg = tid >> 6;
        float off = 0.0f;
        #pragma unroll
        for (int s = 0; s < 3; ++s)
            if (s < seg) off += S[s][cc];
        OFF[seg][cc] = off;
    }
    __syncthreads();
    float* outp = rowsum + (size_t)(n*HF + h) * (WF * C_CH);
    for (int idx = tid; idx < WF * C_CH; idx += 256) {
        const int w  = idx >> 6;
        const int cc = idx & 63;
        outp[idx] = T[w*65 + cc] + OFF[w/44][cc];
    }
}

// ---------------- Kernel 2: column cumsum -> integral image [n][h][x][c] --------------
// Block per (n,x). Thread-quad hq register-scans 16 h values; LDS only for totals.
__global__ __launch_bounds__(256) void k_colcum(const float* __restrict__ rowsum,
                                                float* __restrict__ integ)
{
    __shared__ float tA[4][C_CH];
    const int x  = blockIdx.x;
    const int n  = blockIdx.y;
    const int c  = threadIdx.x & 63;
    const int hq = threadIdx.x >> 6;

    const float* base = rowsum + (size_t)n*HF*WF*C_CH + (size_t)x * C_CH + c;
    float e[16];
    #pragma unroll
    for (int i = 0; i < 16; ++i)
        e[i] = base[(size_t)(hq*16 + i) * (WF*C_CH)];
    #pragma unroll
    for (int i = 1; i < 16; ++i)
        e[i] += e[i-1];
    tA[hq][c] = e[15];
    __syncthreads();
    float off = 0.0f;
    #pragma unroll
    for (int s = 0; s < 3; ++s)
        if (s < hq) off += tA[s][c];
    float* outp = integ + (size_t)n*HF*WF*C_CH + (size_t)x * C_CH + c;
    #pragma unroll
    for (int i = 0; i < 16; ++i)
        outp[(size_t)(hq*16 + i) * (WF*C_CH)] = e[i] + off;
}

// ---------------- Kernel 3: project 8 voxel corners + bbox + offsets ------------------
__global__ void k_boxproj(const float* __restrict__ ks,
                          const float* __restrict__ imu2cs,
                          const float* __restrict__ post_rots,
                          const float* __restrict__ post_trans,
                          const float* __restrict__ undists,
                          const float* __restrict__ grid,
                          BoxP* __restrict__ bp)
{
    const int idx = blockIdx.x * blockDim.x + threadIdx.x;
    if (idx >= NCAM * NH * NP) return;
    const int n  = idx / (NH * NP);
    const int r  = idx % (NH * NP);
    const int nh = r / NP;
    const int p  = r % NP;
    const int d  = p / WDIM;
    const int wd = p % WDIM;

    const float* k  = ks         + n * 9;
    const float* m  = imu2cs     + n * 12;
    const float* pr = post_rots  + n * 9;
    const float* pt = post_trans + n * 3;
    const float* D  = undists    + n * 7;

    float cal[12];
    #pragma unroll
    for (int i = 0; i < 3; ++i)
        #pragma unroll
        for (int j = 0; j < 4; ++j)
            cal[i*4+j] = k[i*3+0]*m[0*4+j] + k[i*3+1]*m[1*4+j] + k[i*3+2]*m[2*4+j];

    const float fx = k[0], fy = k[4], cx = k[2], cy = k[5];
    const bool fish = (D[6] == 1.0f);
    const float D0 = D[0], D1 = D[1], D2 = D[2], D3 = D[3], D4 = D[4], D5 = D[5];

    float left = 1e30f, right = -1e30f, top = 1e30f, bot = -1e30f;
    #pragma unroll
    for (int a = 0; a < 2; ++a) {
        const float vy = 2.0f - (float)(nh + a);   // ys = -arange(0,4)+2
        #pragma unroll
        for (int b = 0; b < 2; ++b) {
            #pragma unroll
            for (int cc = 0; cc < 2; ++cc) {
                const int gz = d + b, gx = wd + cc;
                const float vx = grid[(gz*GDIM + gx)*3 + 0];
                const float vz = grid[(gz*GDIM + gx)*3 + 2];

                const float hx = cal[0]*vx + cal[1]*vy + cal[2]*vz  + cal[3];
                const float hy = cal[4]*vx + cal[5]*vy + cal[6]*vz  + cal[7];
                const float hz = cal[8]*vx + cal[9]*vy + cal[10]*vz + cal[11];

                const float fl = (hz > 0.0f) ? 1.0f : 0.0f;
                const float px = (hx * fl) / hz;
                const float py = (hy * fl) / hz;

                const float x = (px - cx) / fx;
                const float y = (py - cy) / fy;

                float xd, yd;
                if (fish) {
                    const float rr = sqrtf(x*x + y*y);
                    const float th = atanf(rr);
                    const float t2 = th * th;
                    const float t4 = t2 * t2;
                    const float rad = th * (1.0f + D0*t2 + D1*t4 + D2*(t2*t4) + D5*(t4*t4)) / rr;
                    xd = x * rad * fx + cx;
                    yd = y * rad * fy + cy;
                } else {
                    const float r2 = x*x + y*y;
                    const float poly = 1.0f + D0*r2 + D1*r2*r2 + D2*r2*r2*r2;
                    const float xdd = x*poly + (2.0f*D3*x*y + D4*(r2 + 2.0f*x*x));
                    const float ydd = y*poly + (D3*(r2 + 2.0f*y*y) + 2.0f*D4*x*y);
                    xd = xdd * fx + cx;
                    yd = ydd * fy + cy;
                }
                xd *= fl; yd *= fl;

                const float qx = pr[0]*xd + pr[1]*yd + pt[0];
                const float qy = pr[3]*xd + pr[4]*yd + pt[1];
                const float ncx = fminf(fmaxf(2.0f*qx - 1.0f, -1.0f), 1.0f);
                const float ncy = fminf(fmaxf(2.0f*qy - 1.0f, -1.0f), 1.0f);

                left  = fminf(left,  ncx);  right = fmaxf(right, ncx);
                top   = fminf(top,   ncy);  bot   = fmaxf(bot,   ncy);
            }
        }
    }

    const float area = (right - left) * (bot - top) * (float)HF * (float)WF * 0.25f + 1e-6f;

    const float xLp = fminf(fmaxf((left  + 1.0f) * 0.5f * (float)(WF-1), 0.0f), (float)(WF-1));
    const float xRp = fminf(fmaxf((right + 1.0f) * 0.5f * (float)(WF-1), 0.0f), (float)(WF-1));
    const float yTp = fminf(fmaxf((top   + 1.0f) * 0.5f * (float)(HF-1), 0.0f), (float)(HF-1));
    const float yBp = fminf(fmaxf((bot   + 1.0f) * 0.5f * (float)(HF-1), 0.0f), (float)(HF-1));
    const float xL0 = floorf(xLp), xR0 = floorf(xRp), yT0 = floorf(yTp), yB0 = floorf(yBp);

    const int ixL0 = (int)xL0, ixR0 = (int)xR0, iyT0 = (int)yT0, iyB0 = (int)yB0;
    const int ixL1 = min(ixL0 + 1, WF-1), ixR1 = min(ixR0 + 1, WF-1);
    const int iyT1 = min(iyT0 + 1, HF-1), iyB1 = min(iyB0 + 1, HF-1);

    BoxP o;
    o.r0 = iyT0 * ROWB; o.r1 = iyT1 * ROWB; o.r2 = iyB0 * ROWB; o.r3 = iyB1 * ROWB;
    o.c0 = ixL0 * COLB; o.c1 = ixL1 * COLB; o.c2 = ixR0 * COLB; o.c3 = ixR1 * COLB;
    o.wxL = xLp - xL0; o.wxR = xRp - xR0; o.wyT = yTp - yT0; o.wyB = yBp - yB0;
    o.area = area; o.pad0 = 0; o.pad1 = 0; o.pad2 = 0;
    bp[idx] = o;
}

// ---------------- Kernel 4: sample integral image, combine, max over cameras ----------
// 2D tile: block = 4 d-rows x 8 wd, one wave per d-row (8 voxels). Within a wave,
// 4 lane-groups of 16 each load one texel-column per instr (float4 = 4 channels/lane):
// 4 dwordx4 loads/body from the 17MB L2-resident integral. Combine factorizes as
// s = sum_i u_i * sum_g v_g * I(row_i,col_g); cross-group via shfl_xor butterfly.
// Explicit one-camera-ahead load pipelining.
__global__ __launch_bounds__(256) void k_sample(const float* __restrict__ integ,
                                                const BoxP* __restrict__ bp,
                                                float* __restrict__ out)
{
    __shared__ float sm[32][68];     // [voxel][channel], 68: 16B-aligned rows
    const int nh   = blockIdx.y;
    const int t    = blockIdx.x;             // 512 tiles
    const int d0   = (t >> 4) * 4;
    const int w0   = (t & 15) * 8;
    const int tid  = threadIdx.x;
    const int wave = __builtin_amdgcn_readfirstlane(tid >> 6);
    const int lane = tid & 63;
    const int g    = lane >> 4;              // texel-column group
    const int q    = lane & 15;              // channel quad (channels 4q..4q+3)
    const int qoff = q * 16;
    const int d    = d0 + wave;

    auto ISSUE = [&](int cam, int pv,
                     float4& v0, float4& v1, float4& v2, float4& v3,
                     float& vg, float& wT, float& wB, float& ar) {
        const BoxP* bb = bp + ((cam*NH + nh)*NP + pv);
        ar = rfl_f(bb->area);
        const int r0 = rfl_i(bb->r0), r1 = rfl_i(bb->r1);
        const int r2 = rfl_i(bb->r2), r3 = rfl_i(bb->r3);
        const int c0 = rfl_i(bb->c0), c1 = rfl_i(bb->c1);
        const int c2 = rfl_i(bb->c2), c3 = rfl_i(bb->c3);
        const float wxL = rfl_f(bb->wxL), wxR = rfl_f(bb->wxR);
        wT = rfl_f(bb->wyT); wB = rfl_f(bb->wyB);
        const int co = (g == 0) ? c0 : (g == 1) ? c1 : (g == 2) ? c2 : c3;
        vg = (g == 0) ? (1.0f - wxL) : (g == 1) ? wxL
           : (g == 2) ? (wxR - 1.0f) : -wxR;
        const char* base = (const char*)integ + (size_t)cam * IMGB + (size_t)(co + qoff);
        v0 = *(const float4*)(base + r0);
        v1 = *(const float4*)(base + r1);
        v2 = *(const float4*)(base + r2);
        v3 = *(const float4*)(base + r3);
    };

    const int pbase = d * WDIM + w0;
    float4 a0, a1, a2, a3; float avg, awT, awB, aar;
    ISSUE(0, pbase, a0, a1, a2, a3, avg, awT, awB, aar);

    #pragma unroll 1
    for (int j = 0; j < 8; ++j) {
        const int pj = pbase + j;
        float4 vm = make_float4(-3.402823466e38f, -3.402823466e38f,
                                -3.402823466e38f, -3.402823466e38f);
        #pragma unroll
        for (int n = 0; n < NCAM; ++n) {
            float4 b0, b1, b2, b3; float bvg, bwT, bwB, bar;
            if (n < 5) {
                ISSUE(n+1, pj, b0, b1, b2, b3, bvg, bwT, bwB, bar);
            } else if (j < 7) {
                ISSUE(0, pj+1, b0, b1, b2, b3, bvg, bwT, bwB, bar);
            } else {
                b0 = a0; b1 = a1; b2 = a2; b3 = a3;
                bvg = avg; bwT = awT; bwB = awB; bar = aar;
            }
            // compute with A
            const float u0 = 1.0f - awT, u1 = awT, u2 = awB - 1.0f, u3 = -awB;
            float px = fmaf(u0, a0.x, fmaf(u1, a1.x, fmaf(u2, a2.x, u3*a3.x))) * avg;
            float py = fmaf(u0, a0.y, fmaf(u1, a1.y, fmaf(u2, a2.y, u3*a3.y))) * avg;
            float pz = fmaf(u0, a0.z, fmaf(u1, a1.z, fmaf(u2, a2.z, u3*a3.z))) * avg;
            float pw = fmaf(u0, a0.w, fmaf(u1, a1.w, fmaf(u2, a2.w, u3*a3.w))) * avg;
            px += __shfl_xor(px, 16, 64); px += __shfl_xor(px, 32, 64);
            py += __shfl_xor(py, 16, 64); py += __shfl_xor(py, 32, 64);
            pz += __shfl_xor(pz, 16, 64); pz += __shfl_xor(pz, 32, 64);
            pw += __shfl_xor(pw, 16, 64); pw += __shfl_xor(pw, 32, 64);
            const float ia = __builtin_amdgcn_rcpf(aar);
            const bool ok = (aar > 1e-6f);
            vm.x = fmaxf(vm.x, ok ? px*ia : 0.0f);
            vm.y = fmaxf(vm.y, ok ? py*ia : 0.0f);
            vm.z = fmaxf(vm.z, ok ? pz*ia : 0.0f);
            vm.w = fmaxf(vm.w, ok ? pw*ia : 0.0f);
            a0 = b0; a1 = b1; a2 = b2; a3 = b3;
            avg = bvg; awT = bwT; awB = bwB; aar = bar;
        }
        if (g == 0) {
            *(float4*)&sm[wave*8 + j][4*q] = vm;   // 16B-aligned (68*4=272 mult of 16)
        }
    }
    __syncthreads();
    for (int idx = tid; idx < C_CH * 32; idx += 256) {
        const int jj = idx & 31;                   // voxel slot in tile
        const int cc = idx >> 5;
        const int dd = d0 + (jj >> 3);
        const int ww = w0 + (jj & 7);
        out[(size_t)(cc*NH + nh)*NP + dd*WDIM + ww] = sm[jj][cc];
    }
}

extern "C" void kernel_launch(void* const* d_in, const int* in_sizes, int n_in,
                              void* d_out, int out_size, void* d_ws, size_t ws_size,
                              hipStream_t stream)
{
    const float* feats      = (const float*)d_in[0];  // [1,6,64,64,176]
    const float* ks         = (const float*)d_in[1];  // [1,6,3,3]
    const float* imu2cs     = (const float*)d_in[2];  // [1,6,3,4]
    const float* post_rots  = (const float*)d_in[3];  // [1,6,3,3]
    const float* post_trans = (const float*)d_in[4];  // [1,6,3]
    const float* undists    = (const float*)d_in[5];  // [1,6,7]
    const float* grid       = (const float*)d_in[6];  // [1,129,129,3]
    float* out = (float*)d_out;                       // [1,192,128,128]

    char* ws = (char*)d_ws;
    size_t off = 0;
    float* rowsum = (float*)(ws + off);
    off += sizeof(float) * (size_t)NCAM * HF * WF * C_CH;
    off = (off + 255) & ~(size_t)255;
    float* integ = (float*)(ws + off);
    off += sizeof(float) * (size_t)NCAM * HF * WF * C_CH;
    off = (off + 255) & ~(size_t)255;
    BoxP* bp = (BoxP*)(ws + off);
    off += sizeof(BoxP) * (size_t)NCAM * NH * NP;
    (void)ws_size; (void)in_sizes; (void)n_in; (void)out_size;

    dim3 g1(HF, NCAM);
    k_rowcum<<<g1, 256, 0, stream>>>(feats, rowsum);

    dim3 g2(WF, NCAM);
    k_colcum<<<g2, 256, 0, stream>>>(rowsum, integ);

    dim3 g3((NCAM*NH*NP + 255)/256);
    k_boxproj<<<g3, 256, 0, stream>>>(ks, imu2cs, post_rots, post_trans, undists, grid, bp);

    dim3 g4(512, NH);
    k_sample<<<g4, 256, 0, stream>>>(integ, bp, out);
}

// Round 6
// 152.145 us; speedup vs baseline: 1.1167x; 1.1167x over previous
//
#include <hip/hip_runtime.h>
#include <math.h>

#define NCAM 6
#define C_CH 64
#define HF   64
#define WF   176
#define GDIM 129
#define NY   4
#define NH   3
#define DD   128
#define WDIM 128
#define NP   (DD*WDIM)

#define ROWB (WF*C_CH*4)          // integral row stride, bytes (45056)
#define COLB (C_CH*4)             // integral col stride, bytes (256)
#define IMGB ((size_t)HF*WF*C_CH*4)

// Packed box params, 32B = 8 dwords, laid out [nh][p][cam] (one voxel's 6 cams
// contiguous = 192B). dword0 = yT0|yB0<<8|xL0<<16|xR0<<24; 1..4 = wxL,wxR,wyT,wyB;
// 5 = area. Clamps dropped: boundary lerp weights are exactly 0 (integ padded).

__device__ __forceinline__ float bcf(int x) {
    return __builtin_bit_cast(float, x);
}

// ---------------- Kernel 1: row cumsum (axis=-1) -> channel-last rowsum ----------------
__global__ __launch_bounds__(256) void k_rowcum(const float* __restrict__ feat,
                                                float* __restrict__ rowsum)
{
    __shared__ float T[WF * 65];
    __shared__ float S[4][C_CH];
    __shared__ float OFF[4][C_CH];
    const int h   = blockIdx.x;
    const int n   = blockIdx.y;
    const int tid = threadIdx.x;

    for (int idx = tid; idx < C_CH * WF; idx += 256) {
        const int cc = idx / WF;
        const int w  = idx % WF;
        T[w*65 + cc] = feat[((size_t)(n*C_CH + cc)*HF + h)*WF + w];
    }
    __syncthreads();
    {
        const int cc = tid & 63, seg = tid >> 6;
        const int w0 = seg * 44;
        float run = 0.0f;
        #pragma unroll
        for (int i = 0; i < 44; ++i) {
            run += T[(w0 + i)*65 + cc];
            T[(w0 + i)*65 + cc] = run;
        }
        S[seg][cc] = run;
    }
    __syncthreads();
    {
        const int cc = tid & 63, seg = tid >> 6;
        float off = 0.0f;
        #pragma unroll
        for (int s = 0; s < 3; ++s)
            if (s < seg) off += S[s][cc];
        OFF[seg][cc] = off;
    }
    __syncthreads();
    float* outp = rowsum + (size_t)(n*HF + h) * (WF * C_CH);
    for (int idx = tid; idx < WF * C_CH; idx += 256) {
        const int w  = idx >> 6;
        const int cc = idx & 63;
        outp[idx] = T[w*65 + cc] + OFF[w/44][cc];
    }
}

// ---------------- Kernel 2: column cumsum IN PLACE -> integral [n][h][x][c] -----------
__global__ __launch_bounds__(256) void k_colcum(float* __restrict__ integ)
{
    __shared__ float tA[4][C_CH];
    const int x  = blockIdx.x;
    const int n  = blockIdx.y;
    const int c  = threadIdx.x & 63;
    const int hq = threadIdx.x >> 6;

    float* base = integ + (size_t)n*HF*WF*C_CH + (size_t)x * C_CH + c;
    float e[16];
    #pragma unroll
    for (int i = 0; i < 16; ++i)
        e[i] = base[(size_t)(hq*16 + i) * (WF*C_CH)];
    #pragma unroll
    for (int i = 1; i < 16; ++i)
        e[i] += e[i-1];
    tA[hq][c] = e[15];
    __syncthreads();
    float off = 0.0f;
    #pragma unroll
    for (int s = 0; s < 3; ++s)
        if (s < hq) off += tA[s][c];
    #pragma unroll
    for (int i = 0; i < 16; ++i)
        base[(size_t)(hq*16 + i) * (WF*C_CH)] = e[i] + off;
}

// ---------------- Kernel 3: project 8 voxel corners + bbox -> packed params -----------
// Thread idx = (nh, p, cam) with cam fastest -> coalesced 32B writes per voxel group.
__global__ void k_boxproj(const float* __restrict__ ks,
                          const float* __restrict__ imu2cs,
                          const float* __restrict__ post_rots,
                          const float* __restrict__ post_trans,
                          const float* __restrict__ undists,
                          const float* __restrict__ grid,
                          int4* __restrict__ bp)
{
    const int idx = blockIdx.x * blockDim.x + threadIdx.x;
    if (idx >= NCAM * NH * NP) return;
    const int vox = idx / NCAM;
    const int n   = idx - vox * NCAM;
    const int nh  = vox / NP;
    const int p   = vox - nh * NP;
    const int d   = p / WDIM;
    const int wd  = p - d * WDIM;

    const float* k  = ks         + n * 9;
    const float* m  = imu2cs     + n * 12;
    const float* pr = post_rots  + n * 9;
    const float* pt = post_trans + n * 3;
    const float* D  = undists    + n * 7;

    float cal[12];
    #pragma unroll
    for (int i = 0; i < 3; ++i)
        #pragma unroll
        for (int j = 0; j < 4; ++j)
            cal[i*4+j] = k[i*3+0]*m[0*4+j] + k[i*3+1]*m[1*4+j] + k[i*3+2]*m[2*4+j];

    const float fx = k[0], fy = k[4], cx = k[2], cy = k[5];
    const bool fish = (D[6] == 1.0f);
    const float D0 = D[0], D1 = D[1], D2 = D[2], D3 = D[3], D4 = D[4], D5 = D[5];

    float left = 1e30f, right = -1e30f, top = 1e30f, bot = -1e30f;
    #pragma unroll
    for (int a = 0; a < 2; ++a) {
        const float vy = 2.0f - (float)(nh + a);   // ys = -arange(0,4)+2
        #pragma unroll
        for (int b = 0; b < 2; ++b) {
            #pragma unroll
            for (int cc = 0; cc < 2; ++cc) {
                const int gz = d + b, gx = wd + cc;
                const float vx = grid[(gz*GDIM + gx)*3 + 0];
                const float vz = grid[(gz*GDIM + gx)*3 + 2];

                const float hx = cal[0]*vx + cal[1]*vy + cal[2]*vz  + cal[3];
                const float hy = cal[4]*vx + cal[5]*vy + cal[6]*vz  + cal[7];
                const float hz = cal[8]*vx + cal[9]*vy + cal[10]*vz + cal[11];

                const float fl = (hz > 0.0f) ? 1.0f : 0.0f;
                const float px = (hx * fl) / hz;
                const float py = (hy * fl) / hz;

                const float x = (px - cx) / fx;
                const float y = (py - cy) / fy;

                float xd, yd;
                if (fish) {
                    const float rr = sqrtf(x*x + y*y);
                    const float th = atanf(rr);
                    const float t2 = th * th;
                    const float t4 = t2 * t2;
                    const float rad = th * (1.0f + D0*t2 + D1*t4 + D2*(t2*t4) + D5*(t4*t4)) / rr;
                    xd = x * rad * fx + cx;
                    yd = y * rad * fy + cy;
                } else {
                    const float r2 = x*x + y*y;
                    const float poly = 1.0f + D0*r2 + D1*r2*r2 + D2*r2*r2*r2;
                    const float xdd = x*poly + (2.0f*D3*x*y + D4*(r2 + 2.0f*x*x));
                    const float ydd = y*poly + (D3*(r2 + 2.0f*y*y) + 2.0f*D4*x*y);
                    xd = xdd * fx + cx;
                    yd = ydd * fy + cy;
                }
                xd *= fl; yd *= fl;

                const float qx = pr[0]*xd + pr[1]*yd + pt[0];
                const float qy = pr[3]*xd + pr[4]*yd + pt[1];
                const float ncx = fminf(fmaxf(2.0f*qx - 1.0f, -1.0f), 1.0f);
                const float ncy = fminf(fmaxf(2.0f*qy - 1.0f, -1.0f), 1.0f);

                left  = fminf(left,  ncx);  right = fmaxf(right, ncx);
                top   = fminf(top,   ncy);  bot   = fmaxf(bot,   ncy);
            }
        }
    }

    const float area = (right - left) * (bot - top) * (float)HF * (float)WF * 0.25f + 1e-6f;

    const float xLp = fminf(fmaxf((left  + 1.0f) * 0.5f * (float)(WF-1), 0.0f), (float)(WF-1));
    const float xRp = fminf(fmaxf((right + 1.0f) * 0.5f * (float)(WF-1), 0.0f), (float)(WF-1));
    const float yTp = fminf(fmaxf((top   + 1.0f) * 0.5f * (float)(HF-1), 0.0f), (float)(HF-1));
    const float yBp = fminf(fmaxf((bot   + 1.0f) * 0.5f * (float)(HF-1), 0.0f), (float)(HF-1));
    const float xL0 = floorf(xLp), xR0 = floorf(xRp), yT0 = floorf(yTp), yB0 = floorf(yBp);

    const int pyx = (int)yT0 | ((int)yB0 << 8) | ((int)xL0 << 16) | ((int)xR0 << 24);

    int4 o0, o1;
    o0.x = pyx;
    o0.y = __builtin_bit_cast(int, xLp - xL0);
    o0.z = __builtin_bit_cast(int, xRp - xR0);
    o0.w = __builtin_bit_cast(int, yTp - yT0);
    o1.x = __builtin_bit_cast(int, yBp - yB0);
    o1.y = __builtin_bit_cast(int, area);
    o1.z = 0; o1.w = 0;
    bp[(size_t)idx*2 + 0] = o0;
    bp[(size_t)idx*2 + 1] = o1;
}

// ---------------- Kernel 4: sample integral image, combine, max over cameras ----------
// 768 blocks (single co-resident round), 4 waves/block, wave = 16 consecutive voxels,
// lane = channel. Per voxel: ONE vector load prefetches all 6 cams' packed params one
// voxel ahead (decoded via constant-lane readlane -> scalar pipe); all 96 texel dword
// loads issue before any compute (t[6][16] in VGPRs). No cross-lane ops.
__global__ __launch_bounds__(256, 4) void k_sample(const float* __restrict__ integ,
                                                   const int* __restrict__ bpi,
                                                   float* __restrict__ out)
{
    __shared__ float sm[64][65];
    const int nh   = blockIdx.y;
    const int p0   = blockIdx.x * 64;
    const int tid  = threadIdx.x;
    const int wave = __builtin_amdgcn_readfirstlane(tid >> 6);
    const int c    = tid & 63;
    const int pl   = (c < 48) ? c : (c - 48);    // dword index within 192B param block

    const int* bpw = bpi + (size_t)(nh*NP + p0 + wave*16) * 48;

    int vpc = bpw[pl];                            // params for j=0
    #pragma unroll 1
    for (int j = 0; j < 16; ++j) {
        int vpn = vpc;
        if (j < 15) vpn = bpw[(j + 1) * 48 + pl]; // prefetch next voxel's params

        float t[6][16];
        float wxl[6], wxr[6], wyt[6], wyb[6], ar[6];
        #pragma unroll
        for (int cam = 0; cam < 6; ++cam) {
            const int f0 = __builtin_amdgcn_readlane(vpc, cam*8 + 0);
            wxl[cam] = bcf(__builtin_amdgcn_readlane(vpc, cam*8 + 1));
            wxr[cam] = bcf(__builtin_amdgcn_readlane(vpc, cam*8 + 2));
            wyt[cam] = bcf(__builtin_amdgcn_readlane(vpc, cam*8 + 3));
            wyb[cam] = bcf(__builtin_amdgcn_readlane(vpc, cam*8 + 4));
            ar[cam]  = bcf(__builtin_amdgcn_readlane(vpc, cam*8 + 5));
            const int yT = f0 & 255, yB = (f0 >> 8) & 255;
            const int xL = (f0 >> 16) & 255, xR = (f0 >> 24) & 255;
            const int r0 = yT * ROWB, r2 = yB * ROWB;
            const int c0 = xL * COLB, c2 = xR * COLB;
            const char* b = (const char*)integ + (size_t)cam * IMGB;
            #pragma unroll
            for (int rr = 0; rr < 4; ++rr) {
                const int ro = ((rr < 2) ? r0 : r2) + ((rr & 1) ? ROWB : 0);
                #pragma unroll
                for (int cc2 = 0; cc2 < 4; ++cc2) {
                    const int co = ((cc2 < 2) ? c0 : c2) + ((cc2 & 1) ? COLB : 0);
                    t[cam][rr*4 + cc2] = ((const float*)(b + (size_t)(ro + co)))[c];
                }
            }
        }

        float vmax = -3.402823466e38f;
        #pragma unroll
        for (int cam = 0; cam < 6; ++cam) {
            const float A0 = fmaf(wxl[cam], t[cam][1]  - t[cam][0],  t[cam][0]);
            const float B0 = fmaf(wxr[cam], t[cam][3]  - t[cam][2],  t[cam][2]);
            const float A1 = fmaf(wxl[cam], t[cam][5]  - t[cam][4],  t[cam][4]);
            const float B1 = fmaf(wxr[cam], t[cam][7]  - t[cam][6],  t[cam][6]);
            const float A2 = fmaf(wxl[cam], t[cam][9]  - t[cam][8],  t[cam][8]);
            const float B2 = fmaf(wxr[cam], t[cam][11] - t[cam][10], t[cam][10]);
            const float A3 = fmaf(wxl[cam], t[cam][13] - t[cam][12], t[cam][12]);
            const float B3 = fmaf(wxr[cam], t[cam][15] - t[cam][14], t[cam][14]);
            const float d0 = A0 - B0, d1 = A1 - B1;
            const float e0 = B2 - A2, e1 = B3 - A3;
            const float s = fmaf(wyt[cam], d1 - d0, d0) + fmaf(wyb[cam], e1 - e0, e0);
            float v = s * __builtin_amdgcn_rcpf(ar[cam]);
            v = (ar[cam] > 1e-6f) ? v : 0.0f;    // reference: vox * (area > EPS)
            vmax = fmaxf(vmax, v);
        }
        sm[wave*16 + j][c] = vmax;
        vpc = vpn;
    }
    __syncthreads();
    #pragma unroll
    for (int it = 0; it < 16; ++it) {
        const int idx = it*256 + tid;
        const int jj = idx & 63;
        const int cc = idx >> 6;
        out[(size_t)(cc*NH + nh)*NP + p0 + jj] = sm[jj][cc];
    }
}

extern "C" void kernel_launch(void* const* d_in, const int* in_sizes, int n_in,
                              void* d_out, int out_size, void* d_ws, size_t ws_size,
                              hipStream_t stream)
{
    const float* feats      = (const float*)d_in[0];  // [1,6,64,64,176]
    const float* ks         = (const float*)d_in[1];  // [1,6,3,3]
    const float* imu2cs     = (const float*)d_in[2];  // [1,6,3,4]
    const float* post_rots  = (const float*)d_in[3];  // [1,6,3,3]
    const float* post_trans = (const float*)d_in[4];  // [1,6,3]
    const float* undists    = (const float*)d_in[5];  // [1,6,7]
    const float* grid       = (const float*)d_in[6];  // [1,129,129,3]
    float* out = (float*)d_out;                       // [1,192,128,128]

    char* ws = (char*)d_ws;
    size_t off = 0;
    float* integ = (float*)(ws + off);                // rowsum, then integral (in place)
    off += (size_t)NCAM * IMGB + 65536;               // +64KB pad for clamp-free overreads
    off = (off + 255) & ~(size_t)255;
    int4* bp = (int4*)(ws + off);
    off += (size_t)NCAM * NH * NP * 32 + 256;
    (void)ws_size; (void)in_sizes; (void)n_in; (void)out_size;

    dim3 g1(HF, NCAM);
    k_rowcum<<<g1, 256, 0, stream>>>(feats, integ);

    dim3 g2(WF, NCAM);
    k_colcum<<<g2, 256, 0, stream>>>(integ);

    dim3 g3((NCAM*NH*NP + 255)/256);
    k_boxproj<<<g3, 256, 0, stream>>>(ks, imu2cs, post_rots, post_trans, undists, grid, bp);

    dim3 g4(NP/64, NH);
    k_sample<<<g4, 256, 0, stream>>>(integ, (const int*)bp, out);
}

// Round 7
// 148.585 us; speedup vs baseline: 1.1435x; 1.0240x over previous
//
#include <hip/hip_runtime.h>
#include <math.h>

#define NCAM 6
#define C_CH 64
#define HF   64
#define WF   176
#define GDIM 129
#define NY   4
#define NH   3
#define DD   128
#define WDIM 128
#define NP   (DD*WDIM)

#define ROWB (WF*C_CH*4)          // integral row stride, bytes (45056)
#define COLB (C_CH*4)             // integral col stride, bytes (256)
#define IMGB ((size_t)HF*WF*C_CH*4)

// Packed box params, 32B = 8 dwords, laid out [nh][p][cam] (one voxel's 6 cams
// contiguous = 192B). dword0 = yT0|yB0<<8|xL0<<16|xR0<<24; 1..4 = wxL,wxR,wyT,wyB;
// 5 = area. Clamps dropped: boundary lerp weights are exactly 0 (integ padded).

__device__ __forceinline__ float bcf(int x) {
    return __builtin_bit_cast(float, x);
}

// ---------------- Kernel 1: row cumsum (axis=-1) -> channel-last rowsum ----------------
__global__ __launch_bounds__(256) void k_rowcum(const float* __restrict__ feat,
                                                float* __restrict__ rowsum)
{
    __shared__ float T[WF * 65];
    __shared__ float S[4][C_CH];
    __shared__ float OFF[4][C_CH];
    const int h   = blockIdx.x;
    const int n   = blockIdx.y;
    const int tid = threadIdx.x;

    for (int idx = tid; idx < C_CH * WF; idx += 256) {
        const int cc = idx / WF;
        const int w  = idx % WF;
        T[w*65 + cc] = feat[((size_t)(n*C_CH + cc)*HF + h)*WF + w];
    }
    __syncthreads();
    {
        const int cc = tid & 63, seg = tid >> 6;
        const int w0 = seg * 44;
        float run = 0.0f;
        #pragma unroll
        for (int i = 0; i < 44; ++i) {
            run += T[(w0 + i)*65 + cc];
            T[(w0 + i)*65 + cc] = run;
        }
        S[seg][cc] = run;
    }
    __syncthreads();
    {
        const int cc = tid & 63, seg = tid >> 6;
        float off = 0.0f;
        #pragma unroll
        for (int s = 0; s < 3; ++s)
            if (s < seg) off += S[s][cc];
        OFF[seg][cc] = off;
    }
    __syncthreads();
    float* outp = rowsum + (size_t)(n*HF + h) * (WF * C_CH);
    for (int idx = tid; idx < WF * C_CH; idx += 256) {
        const int w  = idx >> 6;
        const int cc = idx & 63;
        outp[idx] = T[w*65 + cc] + OFF[w/44][cc];
    }
}

// ---------------- Kernel 2: column cumsum IN PLACE -> integral [n][h][x][c] -----------
__global__ __launch_bounds__(256) void k_colcum(float* __restrict__ integ)
{
    __shared__ float tA[4][C_CH];
    const int x  = blockIdx.x;
    const int n  = blockIdx.y;
    const int c  = threadIdx.x & 63;
    const int hq = threadIdx.x >> 6;

    float* base = integ + (size_t)n*HF*WF*C_CH + (size_t)x * C_CH + c;
    float e[16];
    #pragma unroll
    for (int i = 0; i < 16; ++i)
        e[i] = base[(size_t)(hq*16 + i) * (WF*C_CH)];
    #pragma unroll
    for (int i = 1; i < 16; ++i)
        e[i] += e[i-1];
    tA[hq][c] = e[15];
    __syncthreads();
    float off = 0.0f;
    #pragma unroll
    for (int s = 0; s < 3; ++s)
        if (s < hq) off += tA[s][c];
    #pragma unroll
    for (int i = 0; i < 16; ++i)
        base[(size_t)(hq*16 + i) * (WF*C_CH)] = e[i] + off;
}

// ---------------- Kernel 3: project 8 voxel corners + bbox -> packed params -----------
__global__ void k_boxproj(const float* __restrict__ ks,
                          const float* __restrict__ imu2cs,
                          const float* __restrict__ post_rots,
                          const float* __restrict__ post_trans,
                          const float* __restrict__ undists,
                          const float* __restrict__ grid,
                          int4* __restrict__ bp)
{
    const int idx = blockIdx.x * blockDim.x + threadIdx.x;
    if (idx >= NCAM * NH * NP) return;
    const int vox = idx / NCAM;
    const int n   = idx - vox * NCAM;
    const int nh  = vox / NP;
    const int p   = vox - nh * NP;
    const int d   = p / WDIM;
    const int wd  = p - d * WDIM;

    const float* k  = ks         + n * 9;
    const float* m  = imu2cs     + n * 12;
    const float* pr = post_rots  + n * 9;
    const float* pt = post_trans + n * 3;
    const float* D  = undists    + n * 7;

    float cal[12];
    #pragma unroll
    for (int i = 0; i < 3; ++i)
        #pragma unroll
        for (int j = 0; j < 4; ++j)
            cal[i*4+j] = k[i*3+0]*m[0*4+j] + k[i*3+1]*m[1*4+j] + k[i*3+2]*m[2*4+j];

    const float fx = k[0], fy = k[4], cx = k[2], cy = k[5];
    const float rfx = 1.0f / fx, rfy = 1.0f / fy;
    const bool fish = (D[6] == 1.0f);
    const float D0 = D[0], D1 = D[1], D2 = D[2], D3 = D[3], D4 = D[4], D5 = D[5];

    float left = 1e30f, right = -1e30f, top = 1e30f, bot = -1e30f;
    #pragma unroll
    for (int a = 0; a < 2; ++a) {
        const float vy = 2.0f - (float)(nh + a);   // ys = -arange(0,4)+2
        #pragma unroll
        for (int b = 0; b < 2; ++b) {
            #pragma unroll
            for (int cc = 0; cc < 2; ++cc) {
                const int gz = d + b, gx = wd + cc;
                const float vx = grid[(gz*GDIM + gx)*3 + 0];
                const float vz = grid[(gz*GDIM + gx)*3 + 2];

                const float hx = cal[0]*vx + cal[1]*vy + cal[2]*vz  + cal[3];
                const float hy = cal[4]*vx + cal[5]*vy + cal[6]*vz  + cal[7];
                const float hz = cal[8]*vx + cal[9]*vy + cal[10]*vz + cal[11];

                const float fl = (hz > 0.0f) ? 1.0f : 0.0f;
                const float rhz = __builtin_amdgcn_rcpf(hz);
                const float px = (hx * fl) * rhz;
                const float py = (hy * fl) * rhz;

                const float x = (px - cx) * rfx;
                const float y = (py - cy) * rfy;

                float xd, yd;
                if (fish) {
                    const float rr = sqrtf(x*x + y*y);
                    const float th = atanf(rr);
                    const float t2 = th * th;
                    const float t4 = t2 * t2;
                    const float rad = th * (1.0f + D0*t2 + D1*t4 + D2*(t2*t4) + D5*(t4*t4))
                                      * __builtin_amdgcn_rcpf(rr);
                    xd = x * rad * fx + cx;
                    yd = y * rad * fy + cy;
                } else {
                    const float r2 = x*x + y*y;
                    const float poly = 1.0f + D0*r2 + D1*r2*r2 + D2*r2*r2*r2;
                    const float xdd = x*poly + (2.0f*D3*x*y + D4*(r2 + 2.0f*x*x));
                    const float ydd = y*poly + (D3*(r2 + 2.0f*y*y) + 2.0f*D4*x*y);
                    xd = xdd * fx + cx;
                    yd = ydd * fy + cy;
                }
                xd *= fl; yd *= fl;

                const float qx = pr[0]*xd + pr[1]*yd + pt[0];
                const float qy = pr[3]*xd + pr[4]*yd + pt[1];
                const float ncx = fminf(fmaxf(2.0f*qx - 1.0f, -1.0f), 1.0f);
                const float ncy = fminf(fmaxf(2.0f*qy - 1.0f, -1.0f), 1.0f);

                left  = fminf(left,  ncx);  right = fmaxf(right, ncx);
                top   = fminf(top,   ncy);  bot   = fmaxf(bot,   ncy);
            }
        }
    }

    const float area = (right - left) * (bot - top) * (float)HF * (float)WF * 0.25f + 1e-6f;

    const float xLp = fminf(fmaxf((left  + 1.0f) * 0.5f * (float)(WF-1), 0.0f), (float)(WF-1));
    const float xRp = fminf(fmaxf((right + 1.0f) * 0.5f * (float)(WF-1), 0.0f), (float)(WF-1));
    const float yTp = fminf(fmaxf((top   + 1.0f) * 0.5f * (float)(HF-1), 0.0f), (float)(HF-1));
    const float yBp = fminf(fmaxf((bot   + 1.0f) * 0.5f * (float)(HF-1), 0.0f), (float)(HF-1));
    const float xL0 = floorf(xLp), xR0 = floorf(xRp), yT0 = floorf(yTp), yB0 = floorf(yBp);

    const int pyx = (int)yT0 | ((int)yB0 << 8) | ((int)xL0 << 16) | ((int)xR0 << 24);

    int4 o0, o1;
    o0.x = pyx;
    o0.y = __builtin_bit_cast(int, xLp - xL0);
    o0.z = __builtin_bit_cast(int, xRp - xR0);
    o0.w = __builtin_bit_cast(int, yTp - yT0);
    o1.x = __builtin_bit_cast(int, yBp - yB0);
    o1.y = __builtin_bit_cast(int, area);
    o1.z = 0; o1.w = 0;
    bp[(size_t)idx*2 + 0] = o0;
    bp[(size_t)idx*2 + 1] = o1;
}

// ---------------- Kernel 4: sample integral image, combine, max over cameras ----------
// 1536 blocks, XCD-swizzled so each XCD's blocks cover a CONTIGUOUS 6144-voxel band
// (per-XCD L2-resident texel footprint). 4 waves/block, wave = 8 voxels, lane = channel.
// Camera-PAIR batching (32 texels in flight, fits 85-VGPR budget at 6 waves/SIMD);
// one-voxel-ahead vector prefetch of packed params, decoded via readlane.
__global__ __launch_bounds__(256, 6) void k_sample(const float* __restrict__ integ,
                                                   const int* __restrict__ bpi,
                                                   float* __restrict__ out)
{
    __shared__ float sm[32][65];
    const int bx   = blockIdx.x;
    const int xcd  = bx & 7;
    const int slot = bx >> 3;
    const int gt   = xcd * 192 + slot;          // contiguous tile band per XCD
    const int nh   = gt >> 9;                    // gt / 512
    const int p0   = (gt & 511) * 32;
    const int tid  = threadIdx.x;
    const int wave = __builtin_amdgcn_readfirstlane(tid >> 6);
    const int c    = tid & 63;
    const int pl   = (c < 48) ? c : (c - 48);    // dword index within 192B param block

    const int* bpw = bpi + (size_t)(nh*NP + p0 + wave*8) * 48;

    int vpc = bpw[pl];                            // params for j=0
    #pragma unroll 1
    for (int j = 0; j < 8; ++j) {
        int vpn = vpc;
        if (j < 7) vpn = bpw[(j + 1) * 48 + pl]; // prefetch next voxel's params

        float vmax = -3.402823466e38f;
        #pragma unroll
        for (int pr2 = 0; pr2 < 3; ++pr2) {
            const int camA = pr2*2, camB = pr2*2 + 1;
            const int fA = __builtin_amdgcn_readlane(vpc, camA*8 + 0);
            const float wxlA = bcf(__builtin_amdgcn_readlane(vpc, camA*8 + 1));
            const float wxrA = bcf(__builtin_amdgcn_readlane(vpc, camA*8 + 2));
            const float wytA = bcf(__builtin_amdgcn_readlane(vpc, camA*8 + 3));
            const float wybA = bcf(__builtin_amdgcn_readlane(vpc, camA*8 + 4));
            const float arA  = bcf(__builtin_amdgcn_readlane(vpc, camA*8 + 5));
            const int fB = __builtin_amdgcn_readlane(vpc, camB*8 + 0);
            const float wxlB = bcf(__builtin_amdgcn_readlane(vpc, camB*8 + 1));
            const float wxrB = bcf(__builtin_amdgcn_readlane(vpc, camB*8 + 2));
            const float wytB = bcf(__builtin_amdgcn_readlane(vpc, camB*8 + 3));
            const float wybB = bcf(__builtin_amdgcn_readlane(vpc, camB*8 + 4));
            const float arB  = bcf(__builtin_amdgcn_readlane(vpc, camB*8 + 5));

            float tA[16], tB[16];
            {
                const int yT = fA & 255, yB2 = (fA >> 8) & 255;
                const int xL = (fA >> 16) & 255, xR = (fA >> 24) & 255;
                const int r0 = yT * ROWB, r2 = yB2 * ROWB;
                const int c0 = xL * COLB, c2 = xR * COLB;
                const char* b = (const char*)integ + (size_t)camA * IMGB;
                #pragma unroll
                for (int rr = 0; rr < 4; ++rr) {
                    const int ro = ((rr < 2) ? r0 : r2) + ((rr & 1) ? ROWB : 0);
                    #pragma unroll
                    for (int cc2 = 0; cc2 < 4; ++cc2) {
                        const int co = ((cc2 < 2) ? c0 : c2) + ((cc2 & 1) ? COLB : 0);
                        tA[rr*4 + cc2] = ((const float*)(b + (size_t)(ro + co)))[c];
                    }
                }
            }
            {
                const int yT = fB & 255, yB2 = (fB >> 8) & 255;
                const int xL = (fB >> 16) & 255, xR = (fB >> 24) & 255;
                const int r0 = yT * ROWB, r2 = yB2 * ROWB;
                const int c0 = xL * COLB, c2 = xR * COLB;
                const char* b = (const char*)integ + (size_t)camB * IMGB;
                #pragma unroll
                for (int rr = 0; rr < 4; ++rr) {
                    const int ro = ((rr < 2) ? r0 : r2) + ((rr & 1) ? ROWB : 0);
                    #pragma unroll
                    for (int cc2 = 0; cc2 < 4; ++cc2) {
                        const int co = ((cc2 < 2) ? c0 : c2) + ((cc2 & 1) ? COLB : 0);
                        tB[rr*4 + cc2] = ((const float*)(b + (size_t)(ro + co)))[c];
                    }
                }
            }

            {
                const float A0 = fmaf(wxlA, tA[1]  - tA[0],  tA[0]);
                const float B0 = fmaf(wxrA, tA[3]  - tA[2],  tA[2]);
                const float A1 = fmaf(wxlA, tA[5]  - tA[4],  tA[4]);
                const float B1 = fmaf(wxrA, tA[7]  - tA[6],  tA[6]);
                const float A2 = fmaf(wxlA, tA[9]  - tA[8],  tA[8]);
                const float B2 = fmaf(wxrA, tA[11] - tA[10], tA[10]);
                const float A3 = fmaf(wxlA, tA[13] - tA[12], tA[12]);
                const float B3 = fmaf(wxrA, tA[15] - tA[14], tA[14]);
                const float d0 = A0 - B0, d1 = A1 - B1;
                const float e0 = B2 - A2, e1 = B3 - A3;
                const float s = fmaf(wytA, d1 - d0, d0) + fmaf(wybA, e1 - e0, e0);
                float v = s * __builtin_amdgcn_rcpf(arA);
                v = (arA > 1e-6f) ? v : 0.0f;
                vmax = fmaxf(vmax, v);
            }
            {
                const float A0 = fmaf(wxlB, tB[1]  - tB[0],  tB[0]);
                const float B0 = fmaf(wxrB, tB[3]  - tB[2],  tB[2]);
                const float A1 = fmaf(wxlB, tB[5]  - tB[4],  tB[4]);
                const float B1 = fmaf(wxrB, tB[7]  - tB[6],  tB[6]);
                const float A2 = fmaf(wxlB, tB[9]  - tB[8],  tB[8]);
                const float B2 = fmaf(wxrB, tB[11] - tB[10], tB[10]);
                const float A3 = fmaf(wxlB, tB[13] - tB[12], tB[12]);
                const float B3 = fmaf(wxrB, tB[15] - tB[14], tB[14]);
                const float d0 = A0 - B0, d1 = A1 - B1;
                const float e0 = B2 - A2, e1 = B3 - A3;
                const float s = fmaf(wytB, d1 - d0, d0) + fmaf(wybB, e1 - e0, e0);
                float v = s * __builtin_amdgcn_rcpf(arB);
                v = (arB > 1e-6f) ? v : 0.0f;
                vmax = fmaxf(vmax, v);
            }
        }
        sm[wave*8 + j][c] = vmax;
        vpc = vpn;
    }
    __syncthreads();
    #pragma unroll
    for (int it = 0; it < 8; ++it) {
        const int idx = it*256 + tid;
        const int jj = idx & 31;
        const int cc = idx >> 5;
        out[(size_t)(cc*NH + nh)*NP + p0 + jj] = sm[jj][cc];
    }
}

extern "C" void kernel_launch(void* const* d_in, const int* in_sizes, int n_in,
                              void* d_out, int out_size, void* d_ws, size_t ws_size,
                              hipStream_t stream)
{
    const float* feats      = (const float*)d_in[0];  // [1,6,64,64,176]
    const float* ks         = (const float*)d_in[1];  // [1,6,3,3]
    const float* imu2cs     = (const float*)d_in[2];  // [1,6,3,4]
    const float* post_rots  = (const float*)d_in[3];  // [1,6,3,3]
    const float* post_trans = (const float*)d_in[4];  // [1,6,3]
    const float* undists    = (const float*)d_in[5];  // [1,6,7]
    const float* grid       = (const float*)d_in[6];  // [1,129,129,3]
    float* out = (float*)d_out;                       // [1,192,128,128]

    char* ws = (char*)d_ws;
    size_t off = 0;
    float* integ = (float*)(ws + off);                // rowsum, then integral (in place)
    off += (size_t)NCAM * IMGB + 65536;               // +64KB pad for clamp-free overreads
    off = (off + 255) & ~(size_t)255;
    int4* bp = (int4*)(ws + off);
    off += (size_t)NCAM * NH * NP * 32 + 256;
    (void)ws_size; (void)in_sizes; (void)n_in; (void)out_size;

    dim3 g1(HF, NCAM);
    k_rowcum<<<g1, 256, 0, stream>>>(feats, integ);

    dim3 g2(WF, NCAM);
    k_colcum<<<g2, 256, 0, stream>>>(integ);

    dim3 g3((NCAM*NH*NP + 255)/256);
    k_boxproj<<<g3, 256, 0, stream>>>(ks, imu2cs, post_rots, post_trans, undists, grid, bp);

    dim3 g4(NP/32 * NH);   // 1536 blocks, 1D, XCD-swizzled inside
    k_sample<<<g4, 256, 0, stream>>>(integ, (const int*)bp, out);
}